// Round 1
// baseline (121.283 us; speedup 1.0000x reference)
//
#include <hip/hip_runtime.h>
#include <math.h>

// Problem constants (match reference)
#define HH 256
#define WW 256
#define NPIX (HH * WW)        // 65536
#define NP 512                // points
// ALPHA = -5.0, 1/ALPHA = -0.2

// ws layout (floats):
//   ws[0]        = dmax  (global max distance)
//   ws[1]        = sum(hm * min_dist)
//   ws[2]        = sum(|hm|)
//   ws[3..3+NP)  = S[p] = sum over pixels of w^-5
#define WS_DMAX 0
#define WS_SUM1 1
#define WS_SUM2 2
#define WS_S    3

// ---------------------------------------------------------------------------
// Kernel 1: global max distance. max over grid of dist(p) is attained at a
// grid corner, and d^2 = dy^2 + dx^2 is separable -> max over corners =
// max(dy0^2, dy1^2) + max(dx0^2, dx1^2). One block of 512 threads.
// ---------------------------------------------------------------------------
__global__ __launch_bounds__(NP) void dmax_kernel(const float* __restrict__ pts,
                                                  float* __restrict__ ws) {
    int t = threadIdx.x;  // 0..511
    float py = pts[2 * t + 0];
    float px = pts[2 * t + 1];
    float dy0 = 0.0f - py, dy1 = (float)(HH - 1) - py;
    float dx0 = 0.0f - px, dx1 = (float)(WW - 1) - px;
    float m = fmaxf(dy0 * dy0, dy1 * dy1) + fmaxf(dx0 * dx0, dx1 * dx1);

    for (int off = 32; off; off >>= 1) m = fmaxf(m, __shfl_down(m, off, 64));
    __shared__ float red[8];
    int wid = t >> 6, lane = t & 63;
    if (lane == 0) red[wid] = m;
    __syncthreads();
    if (t == 0) {
        float mm = red[0];
        #pragma unroll
        for (int w = 1; w < 8; ++w) mm = fmaxf(mm, red[w]);
        ws[WS_DMAX] = sqrtf(mm);
    }
}

// ---------------------------------------------------------------------------
// Kernel 2: term 1. One thread per pixel; loop over 512 points in LDS in
// SQUARED distance (sqrt deferred to after the min). Block-reduce the two
// sums, one atomicAdd per block.
// ---------------------------------------------------------------------------
__global__ __launch_bounds__(256) void term1_kernel(const float* __restrict__ hm,
                                                    const float* __restrict__ pts,
                                                    float* __restrict__ ws) {
    __shared__ float4 spts4[NP / 2];  // 512 points * 2 floats = 256 float4
    int tid = threadIdx.x;
    spts4[tid] = ((const float4*)pts)[tid];
    __syncthreads();

    int idx = blockIdx.x * 256 + tid;
    float fi = (float)(idx >> 8);
    float fj = (float)(idx & (WW - 1));

    const float2* sp = (const float2*)spts4;
    float mind2 = 3.4e38f;
    #pragma unroll 8
    for (int p = 0; p < NP; ++p) {
        float2 pt = sp[p];             // broadcast LDS read (conflict-free)
        float dy = fi - pt.x;
        float dx = fj - pt.y;
        float d2 = fmaf(dy, dy, dx * dx);
        mind2 = fminf(mind2, d2);
    }

    float h = hm[idx];
    float v1 = h * sqrtf(mind2);
    float v2 = fabsf(h);

    for (int off = 32; off; off >>= 1) {
        v1 += __shfl_down(v1, off, 64);
        v2 += __shfl_down(v2, off, 64);
    }
    __shared__ float r1[4], r2[4];
    int wid = tid >> 6, lane = tid & 63;
    if (lane == 0) { r1[wid] = v1; r2[wid] = v2; }
    __syncthreads();
    if (tid == 0) {
        atomicAdd(&ws[WS_SUM1], r1[0] + r1[1] + r1[2] + r1[3]);
        atomicAdd(&ws[WS_SUM2], r2[0] + r2[1] + r2[2] + r2[3]);
    }
}

// ---------------------------------------------------------------------------
// Kernel 3: term 2. grid = NP points x 4 pixel-slices = 2048 blocks of 256.
// Each block owns one point p and 1/4 of the pixels; hm read as float4
// (fully L2/L3-resident). w^-5 = (rcp(w))^5 via 3 muls. One atomicAdd per
// block into S[p].
// ---------------------------------------------------------------------------
__global__ __launch_bounds__(256) void term2_kernel(const float* __restrict__ hm,
                                                    const float* __restrict__ pts,
                                                    float* __restrict__ ws) {
    int bid = blockIdx.x;
    int p = bid & (NP - 1);
    int slice = bid >> 9;          // 0..3
    int tid = threadIdx.x;

    float py = pts[2 * p + 0];
    float px = pts[2 * p + 1];
    float dmax = ws[WS_DMAX];

    const float4* hm4 = (const float4*)hm;
    int base4 = slice * (NPIX / 4 / 4);   // 4096 float4 per slice

    float acc = 0.0f;
    #pragma unroll 4
    for (int k = 0; k < 16; ++k) {
        int g = base4 + k * 256 + tid;    // float4 index, coalesced
        float4 h4 = hm4[g];
        int pix0 = g << 2;
        float fi = (float)(pix0 >> 8);
        float fj0 = (float)(pix0 & (WW - 1));   // 4 consecutive pixels, same row
        float dy = fi - py;
        float dy2 = dy * dy;
        float hx[4] = {h4.x, h4.y, h4.z, h4.w};
        #pragma unroll
        for (int c = 0; c < 4; ++c) {
            float dx = fj0 + (float)c - px;
            float d = sqrtf(fmaf(dx, dx, dy2));
            float w = fmaf(hx[c], d - dmax, dmax);   // hm*d + (1-hm)*dmax
            float r = __builtin_amdgcn_rcpf(w);
            float r2 = r * r;
            float r4 = r2 * r2;
            acc = fmaf(r4, r, acc);                  // += w^-5
        }
    }

    for (int off = 32; off; off >>= 1) acc += __shfl_down(acc, off, 64);
    __shared__ float red[4];
    int wid = tid >> 6, lane = tid & 63;
    if (lane == 0) red[wid] = acc;
    __syncthreads();
    if (tid == 0) atomicAdd(&ws[WS_S + p], red[0] + red[1] + red[2] + red[3]);
}

// ---------------------------------------------------------------------------
// Kernel 4: combine. soft_min[p] = (S[p]/65536)^(-1/5); out = ws1/ws2 +
// mean_p soft_min.
// ---------------------------------------------------------------------------
__global__ __launch_bounds__(NP) void final_kernel(const float* __restrict__ ws,
                                                   float* __restrict__ out) {
    int t = threadIdx.x;  // 0..511
    float S = ws[WS_S + t];
    float sm = powf(S * (1.0f / (float)NPIX), -0.2f);

    for (int off = 32; off; off >>= 1) sm += __shfl_down(sm, off, 64);
    __shared__ float red[8];
    int wid = t >> 6, lane = t & 63;
    if (lane == 0) red[wid] = sm;
    __syncthreads();
    if (t == 0) {
        float s = 0.0f;
        #pragma unroll
        for (int w = 0; w < 8; ++w) s += red[w];
        out[0] = ws[WS_SUM1] / ws[WS_SUM2] + s * (1.0f / (float)NP);
    }
}

extern "C" void kernel_launch(void* const* d_in, const int* in_sizes, int n_in,
                              void* d_out, int out_size, void* d_ws, size_t ws_size,
                              hipStream_t stream) {
    const float* hm  = (const float*)d_in[0];   // (256,256) f32
    const float* pts = (const float*)d_in[1];   // (512,2)  f32
    float* ws  = (float*)d_ws;
    float* out = (float*)d_out;

    // zero the accumulators (ws is re-poisoned to 0xAA before every launch)
    hipMemsetAsync(d_ws, 0, (WS_S + NP) * sizeof(float), stream);

    dmax_kernel <<<1,    NP,  0, stream>>>(pts, ws);
    term1_kernel<<<NPIX / 256, 256, 0, stream>>>(hm, pts, ws);
    term2_kernel<<<NP * 4, 256, 0, stream>>>(hm, pts, ws);
    final_kernel<<<1,    NP,  0, stream>>>(ws, out);
}